// Round 6
// baseline (167.106 us; speedup 1.0000x reference)
//
#include <hip/hip_runtime.h>
#include <hip/hip_bf16.h>
#include <math.h>

// Problem constants (fixed by setup_inputs)
constexpr int B_ = 32;
constexpr int P_ = 24564;
constexpr int C_ = 81;
constexpr int K_ = 200;

constexpr int NCH = 64;           // chunks per image
constexpr int CPR = 384;          // rows per chunk; 64*384 = 24576 >= 24564
constexpr int SCAP = 1024;        // per-block LDS staging capacity (expect ~404)
constexpr int CAP  = 512;         // per-task candidate capacity (expect ~322)
constexpr float T_SEL = 0.9869f;  // static prune threshold; mean count ~322 > 200 (6.8 sigma)
                                  // soundness: count>=200 above T => true top-200 all > T;
                                  // violations detected at runtime -> exact fallback.

// ---------------------------------------------------------------------------
// K1 (only conf pass): stream slab coalesced, stage score>T candidates in LDS,
// reserve per-class ranges with ONE global atomic per (block,class), scatter.
// ---------------------------------------------------------------------------
__global__ __launch_bounds__(256) void k_filter(const float* __restrict__ conf,
                                                unsigned long long* __restrict__ cand,
                                                unsigned* __restrict__ cnt,
                                                unsigned* __restrict__ bflag) {
    __shared__ unsigned long long skey[SCAP];   // 8 KB
    __shared__ unsigned short scls[SCAP];       // 2 KB
    __shared__ unsigned scnt[C_], sbase[C_], scnt2[C_];
    __shared__ unsigned sn;
    const int bid = blockIdx.x;
    const int b = bid / NCH, ch = bid % NCH;
    const int tid = threadIdx.x;

    for (int i = tid; i < C_; i += 256) { scnt[i] = 0; scnt2[i] = 0; }
    if (tid == 0) sn = 0;
    __syncthreads();

    const int p0 = ch * CPR;
    const int rows = min(CPR, P_ - p0);
    const float* slab = conf + ((size_t)b * P_ + (size_t)p0) * C_;
    const int n4 = rows * C_ / 4;               // rows%4==0 -> exact
    for (int g = tid; g < n4; g += 256) {
        float4 v = ((const float4*)slab)[g];
        int e = g * 4;
        int c = e % C_;
        int pl = e / C_;
        float s[4] = {v.x, v.y, v.z, v.w};
#pragma unroll
        for (int j = 0; j < 4; ++j) {
            int cj = c + j, pj = pl;
            if (cj >= C_) { cj -= C_; pj += 1; }
            float sv = s[j];
            if (sv > T_SEL && cj != 0) {        // class 0 (background) never output
                unsigned pos = atomicAdd(&sn, 1u);
                if (pos < (unsigned)SCAP) {
                    unsigned pg = (unsigned)(p0 + pj);
                    skey[pos] = ((unsigned long long)__float_as_uint(sv) << 32) | (~pg);
                    scls[pos] = (unsigned short)cj;
                    atomicAdd(&scnt[cj], 1u);
                } else {
                    bflag[b] = 1u;              // staging overflow -> image fallback
                }
            }
        }
    }
    __syncthreads();
    if (tid < C_) sbase[tid] = scnt[tid] ? atomicAdd(&cnt[b * C_ + tid], scnt[tid]) : 0u;
    __syncthreads();
    const int m = (int)min(sn, (unsigned)SCAP);
    for (int i = tid; i < m; i += 256) {
        int c = scls[i];
        unsigned pos = sbase[c] + atomicAdd(&scnt2[c], 1u);
        if (pos < (unsigned)CAP)
            cand[((size_t)(b * C_ + c)) * CAP + pos] = skey[i];
        // pos >= CAP  =>  cnt[task] > CAP  => task falls back (detected in k_nms)
    }
}

// ---------------------------------------------------------------------------
// K2: per-task exact top-200 via barrier-free rank-sort (keys unique), decode,
// IoU masks (register-cached columns), uniform wave-0 greedy scan, write.
// ---------------------------------------------------------------------------
__global__ __launch_bounds__(256) void k_nms(const unsigned long long* __restrict__ cand,
                                             const unsigned* __restrict__ cnt,
                                             const unsigned* __restrict__ bflag,
                                             const float* __restrict__ conf,
                                             const float* __restrict__ loc,
                                             const float* __restrict__ prior,
                                             float* __restrict__ out) {
#pragma clang fp contract(off)
    __shared__ __align__(16) unsigned long long masks[K_][4];   // 6400 B
    __shared__ __align__(16) float outrow[1024];                // 4096 B; aliases buf[512] u64
    __shared__ unsigned long long top[256];                     // 2048 B (rank-ordered, desc)
    __shared__ float sc[K_], bx1[K_], by1[K_], bx2[K_], by2[K_], bar[K_];
    __shared__ unsigned char vflag[K_];
    __shared__ unsigned long long keepw[4];
    __shared__ unsigned kpre[4];
    __shared__ unsigned long long sh_prefix;
    __shared__ unsigned sh_rank, sh_cnt2;

    unsigned long long* buf = (unsigned long long*)outrow;      // 512 u64 staging
    unsigned* rs_hist = (unsigned*)&masks[0][0];                // fb-only scratch (pre-IoU)
    unsigned* rs_sf   = rs_hist + 256;

    const int bid = blockIdx.x;
    const int b = bid / C_, c = bid % C_;
    const int tid = threadIdx.x;
    float* obase = out + ((size_t)(b * C_ + c)) * (K_ * 5);

    if (c == 0) {                               // background rows: all zeros
        float4 z = make_float4(0.f, 0.f, 0.f, 0.f);
        for (int i = tid; i < K_ * 5 / 4; i += 256) ((float4*)obase)[i] = z;
        return;
    }

    const int task = b * C_ + c;
    const unsigned long long* crow = cand + (size_t)task * CAP;
    const unsigned cn = cnt[task];
    const bool fb = (bflag[b] != 0u) || (cn < (unsigned)K_) || (cn > (unsigned)CAP);

    int n;
    if (!fb) {
        n = (int)cn;                            // 200 <= n <= CAP
        for (int i = tid; i < CAP; i += 256)
            buf[i] = (i < n) ? crow[i] : 0ull;
        top[tid] = 0ull;
        __syncthreads();
    } else {
        // ---- exact fallback from the strided global column (rare/never) ----
        for (int i = tid; i < CAP; i += 256) buf[i] = 0ull;
        top[tid] = 0ull;
        const float* col = conf + (size_t)b * P_ * C_ + c;
        unsigned lc = 0;
        for (int p = tid; p < P_; p += 256)
            if (col[(size_t)p * C_] > 0.01f) lc++;
        rs_sf[tid] = lc;
        __syncthreads();
        for (int off = 128; off > 0; off >>= 1) {
            if (tid < off) rs_sf[tid] += rs_sf[tid + off];
            __syncthreads();
        }
        const unsigned total = rs_sf[0];
        unsigned long long t200v = 1ull;
        if (total > (unsigned)K_) {
            if (tid == 0) { sh_prefix = 0ull; sh_rank = (unsigned)K_; }
            __syncthreads();
            for (int d = 7; d >= 0; --d) {
                rs_hist[tid] = 0;
                __syncthreads();
                const unsigned long long pref = sh_prefix;
                const unsigned rank = sh_rank;
                for (int p = tid; p < P_; p += 256) {
                    float sv = col[(size_t)p * C_];
                    if (sv > 0.01f) {
                        unsigned long long key =
                            ((unsigned long long)__float_as_uint(sv) << 32) | (~(unsigned)p);
                        bool match = (d == 7) || (((key ^ pref) >> ((d + 1) * 8)) == 0ull);
                        if (match) atomicAdd(&rs_hist[(unsigned)((key >> (d * 8)) & 255ull)], 1u);
                    }
                }
                __syncthreads();
                rs_sf[tid] = rs_hist[tid];
                __syncthreads();
                for (int off = 1; off < 256; off <<= 1) {
                    unsigned v2 = (tid + off < 256) ? rs_sf[tid + off] : 0u;
                    __syncthreads();
                    rs_sf[tid] += v2;
                    __syncthreads();
                }
                if (rs_sf[tid] >= rank && (tid == 255 || rs_sf[tid + 1] < rank)) {
                    sh_prefix = pref | ((unsigned long long)tid << (d * 8));
                    sh_rank = rank - ((tid == 255) ? 0u : rs_sf[tid + 1]);
                }
                __syncthreads();
            }
            t200v = sh_prefix;
        }
        if (tid == 0) sh_cnt2 = 0;
        __syncthreads();
        for (int p = tid; p < P_; p += 256) {
            float sv = col[(size_t)p * C_];
            if (sv > 0.01f) {
                unsigned long long key =
                    ((unsigned long long)__float_as_uint(sv) << 32) | (~(unsigned)p);
                if (key >= t200v) {
                    unsigned pos = atomicAdd(&sh_cnt2, 1u);
                    if (pos < (unsigned)CAP) buf[pos] = key;   // <=200 qualify (keys unique)
                }
            }
        }
        __syncthreads();
        n = (int)min(sh_cnt2, (unsigned)CAP);   // <= 200
    }

    // ---- exact rank-sort: thread owns keys {tid, tid+256}; rank = #{greater}.
    // Broadcast b128 reads (same address across lanes) are conflict-free; no
    // barriers inside the loop. Unique keys => unique ranks; rank<256 => top-256
    // superset of top-200 in exact descending order. Padding zeros rank >= n.
    {
        const unsigned long long k1 = buf[tid];
        const unsigned long long k2 = buf[tid + 256];
        int r1 = 0, r2 = 0;
        const int nn = (n + 3) & ~3;
        for (int i = 0; i < nn; i += 4) {
            ulonglong2 a = *(const ulonglong2*)&buf[i];
            ulonglong2 bb = *(const ulonglong2*)&buf[i + 2];
            r1 += (a.x > k1) + (a.y > k1) + (bb.x > k1) + (bb.y > k1);
            r2 += (a.x > k2) + (a.y > k2) + (bb.x > k2) + (bb.y > k2);
        }
        if (k1 != 0ull && r1 < 256) top[r1] = k1;
        if (k2 != 0ull && r2 < 256) top[r2] = k2;
    }
    __syncthreads();

    const int nsel = min(n, K_);

    // decode rank-r candidates (top[r] is the (r+1)-th largest)
    if (tid < K_) {
        const int r = tid;
        bool v = (r < nsel);
        float score = 0.f, x1 = 0.f, y1 = 0.f, x2 = 0.f, y2 = 0.f, ar = 0.f;
        if (v) {
            unsigned long long key = top[r];
            unsigned ub = (unsigned)(key >> 32);
            unsigned p = ~((unsigned)key);
            score = __uint_as_float(ub);
            v = ((ub & 0x7F800000u) != 0x7F800000u);   // isfinite
            const float4 l4 = ((const float4*)loc)[(size_t)b * P_ + p];
            const float4 p4 = ((const float4*)prior)[p];
            float cx = p4.x + (l4.x * 0.1f) * p4.z;
            float cy = p4.y + (l4.y * 0.1f) * p4.w;
            float w  = p4.z * expf(l4.z * 0.2f);
            float h  = p4.w * expf(l4.w * 0.2f);
            x1 = cx - w * 0.5f;
            y1 = cy - h * 0.5f;
            x2 = x1 + w;
            y2 = y1 + h;
            ar = (x2 - x1) * (y2 - y1);
        }
        sc[r] = score; bx1[r] = x1; by1[r] = y1; bx2[r] = x2; by2[r] = y2; bar[r] = ar;
        vflag[r] = v ? (unsigned char)1 : (unsigned char)0;
    }
    __syncthreads();                            // decode done; buf dead -> outrow reusable

    for (int i = tid; i < 1024; i += 256) outrow[i] = 0.0f;

    // ---- IoU suppression bitmasks, column boxes register-cached ------------
    const int nv = nsel;
    const int wid = tid >> 6, lane = tid & 63;

    float jx1[4], jy1[4], jx2[4], jy2[4], jar[4];
#pragma unroll
    for (int w = 0; w < 4; ++w) {
        int j = w * 64 + lane;
        bool in = (j < K_);
        jx1[w] = in ? bx1[j] : 0.f;
        jy1[w] = in ? by1[j] : 0.f;
        jx2[w] = in ? bx2[j] : 0.f;
        jy2[w] = in ? by2[j] : 0.f;
        jar[w] = in ? bar[j] : 0.f;
    }

    for (int idx = tid; idx < K_ * 4; idx += 256) {
        int i = idx >> 2, w = idx & 3;
        if (w < (i >> 6)) masks[i][w] = 0ull;
    }
    for (int i = wid; i < nv; i += 4) {
        float r_x1 = bx1[i], r_y1 = by1[i], r_x2 = bx2[i], r_y2 = by2[i], r_ar = bar[i];
        const int w0 = i >> 6;
#pragma unroll
        for (int w = 0; w < 4; ++w) {
            if (w >= w0) {
                int j = w * 64 + lane;
                bool pred = false;
                if (j < nv && j > i) {
                    float xx1 = fmaxf(r_x1, jx1[w]);
                    float yy1 = fmaxf(r_y1, jy1[w]);
                    float xx2 = fminf(r_x2, jx2[w]);
                    float yy2 = fminf(r_y2, jy2[w]);
                    float iw = fmaxf(xx2 - xx1, 0.0f);
                    float ih = fmaxf(yy2 - yy1, 0.0f);
                    float inter = iw * ih;
                    float uni = (r_ar + jar[w]) - inter;
                    pred = (uni > 0.0f) && (inter / uni > 0.45f);
                }
                unsigned long long m = __ballot(pred);
                if (lane == 0) masks[i][w] = m;
            }
        }
    }
    __syncthreads();

    // ---- greedy suppression: wave 0, uniform lanes, kept-nonzero-rows loop.
    if (tid < 64) {
        const int l = tid;
        unsigned long long V0 = __ballot((l       < nv) && vflag[l]);
        unsigned long long V1 = __ballot((64 + l  < nv) && vflag[64 + l]);
        unsigned long long V2 = __ballot((128 + l < nv) && vflag[128 + l]);
        unsigned long long V3 = __ballot((192 + l < nv) && vflag[192 + l]);
        auto rownz = [&](int r) -> bool {
            if (r >= nv) return false;
            return (masks[r][0] | masks[r][1] | masks[r][2] | masks[r][3]) != 0ull;
        };
        unsigned long long R0 = __ballot(rownz(l))       & V0;
        unsigned long long R1 = __ballot(rownz(64 + l))  & V1;
        unsigned long long R2 = __ballot(rownz(128 + l)) & V2;
        unsigned long long R3 = __ballot(rownz(192 + l)) & V3;

        unsigned long long S0 = 0, S1 = 0, S2 = 0, S3 = 0;
        while (true) {
            unsigned long long t;
            int i = -1;
            if ((t = R0 & ~S0) != 0ull)      i = (int)__builtin_ctzll(t);
            else if ((t = R1 & ~S1) != 0ull) i = 64 + (int)__builtin_ctzll(t);
            else if ((t = R2 & ~S2) != 0ull) i = 128 + (int)__builtin_ctzll(t);
            else if ((t = R3 & ~S3) != 0ull) i = 192 + (int)__builtin_ctzll(t);
            if (i < 0) break;
            const unsigned long long bit = 1ull << (i & 63);
            const int slot = i >> 6;
            if (slot == 0) R0 ^= bit; else if (slot == 1) R1 ^= bit;
            else if (slot == 2) R2 ^= bit; else R3 ^= bit;
            ulonglong2 m01 = *(const ulonglong2*)&masks[i][0];
            ulonglong2 m23 = *(const ulonglong2*)&masks[i][2];
            S0 |= m01.x; S1 |= m01.y; S2 |= m23.x; S3 |= m23.y;
        }
        if (l == 0) {
            unsigned long long K0 = V0 & ~S0, K1 = V1 & ~S1, K2 = V2 & ~S2, K3 = V3 & ~S3;
            keepw[0] = K0; keepw[1] = K1; keepw[2] = K2; keepw[3] = K3;
            kpre[0] = 0;
            kpre[1] = (unsigned)__popcll(K0);
            kpre[2] = kpre[1] + (unsigned)__popcll(K1);
            kpre[3] = kpre[2] + (unsigned)__popcll(K2);
        }
    }
    __syncthreads();

    if (tid < nv) {
        int w = tid >> 6, bit = tid & 63;
        if ((keepw[w] >> bit) & 1ull) {
            unsigned slot = kpre[w] + (unsigned)__popcll(keepw[w] & ((1ull << bit) - 1ull));
            outrow[slot * 5 + 0] = sc[tid];
            outrow[slot * 5 + 1] = bx1[tid];
            outrow[slot * 5 + 2] = by1[tid];
            outrow[slot * 5 + 3] = bx2[tid];
            outrow[slot * 5 + 4] = by2[tid];
        }
    }
    __syncthreads();

    for (int i = tid; i < K_ * 5 / 4; i += 256)
        ((float4*)obase)[i] = ((const float4*)outrow)[i];
}

// ---------------------------------------------------------------------------
extern "C" void kernel_launch(void* const* d_in, const int* in_sizes, int n_in,
                              void* d_out, int out_size, void* d_ws, size_t ws_size,
                              hipStream_t stream) {
    const float* loc   = (const float*)d_in[0];
    const float* conf  = (const float*)d_in[1];
    const float* prior = (const float*)d_in[2];
    float* out = (float*)d_out;

    char* ws = (char*)d_ws;
    const size_t candBytes = (size_t)B_ * C_ * CAP * sizeof(unsigned long long); // 10.6 MB
    unsigned long long* cand = (unsigned long long*)ws;
    unsigned* cnt   = (unsigned*)(ws + candBytes);            // B_*C_ counters
    unsigned* bflag = cnt + (size_t)B_ * C_;                  // B_ flags (contiguous)

    hipMemsetAsync(cnt, 0, (size_t)(B_ * C_ + B_) * sizeof(unsigned), stream);

    k_filter<<<B_ * NCH, 256, 0, stream>>>(conf, cand, cnt, bflag);
    k_nms   <<<B_ * C_,  256, 0, stream>>>(cand, cnt, bflag, conf, loc, prior, out);
}

// Round 7
// 156.673 us; speedup vs baseline: 1.0666x; 1.0666x over previous
//
#include <hip/hip_runtime.h>
#include <hip/hip_bf16.h>
#include <math.h>

// Problem constants (fixed by setup_inputs)
constexpr int B_ = 32;
constexpr int P_ = 24564;
constexpr int C_ = 81;
constexpr int K_ = 200;

constexpr int NCH = 64;           // chunks per image
constexpr int CPR = 384;          // rows per chunk; 64*384 = 24576 >= 24564
constexpr int SCAP = 1024;        // per-block LDS staging capacity (expect ~404)
constexpr int CAP  = 512;         // per-task candidate capacity (expect ~322)
constexpr float T_SEL = 0.9869f;  // static prune threshold; mean count ~322 > 200 (6.8 sigma)
                                  // soundness: count>=200 above T => true top-200 all > T;
                                  // violations detected at runtime -> exact fallback.
// All candidate scores lie in (T_SEL, 1.0) => key bits[63:51] constant =>
// bits[50:43] are the discriminating radix digit for the cut.

// ---------------------------------------------------------------------------
// K1 (only conf pass): stream slab coalesced, stage score>T candidates in LDS,
// reserve per-class ranges with ONE global atomic per (block,class), scatter.
// ---------------------------------------------------------------------------
__global__ __launch_bounds__(256) void k_filter(const float* __restrict__ conf,
                                                unsigned long long* __restrict__ cand,
                                                unsigned* __restrict__ cnt,
                                                unsigned* __restrict__ bflag) {
    __shared__ unsigned long long skey[SCAP];   // 8 KB
    __shared__ unsigned short scls[SCAP];       // 2 KB
    __shared__ unsigned scnt[C_], sbase[C_], scnt2[C_];
    __shared__ unsigned sn;
    const int bid = blockIdx.x;
    const int b = bid / NCH, ch = bid % NCH;
    const int tid = threadIdx.x;

    for (int i = tid; i < C_; i += 256) { scnt[i] = 0; scnt2[i] = 0; }
    if (tid == 0) sn = 0;
    __syncthreads();

    const int p0 = ch * CPR;
    const int rows = min(CPR, P_ - p0);
    const float* slab = conf + ((size_t)b * P_ + (size_t)p0) * C_;
    const int n4 = rows * C_ / 4;               // rows%4==0 -> exact
    for (int g = tid; g < n4; g += 256) {
        float4 v = ((const float4*)slab)[g];
        int e = g * 4;
        int c = e % C_;
        int pl = e / C_;
        float s[4] = {v.x, v.y, v.z, v.w};
#pragma unroll
        for (int j = 0; j < 4; ++j) {
            int cj = c + j, pj = pl;
            if (cj >= C_) { cj -= C_; pj += 1; }
            float sv = s[j];
            if (sv > T_SEL && cj != 0) {        // class 0 (background) never output
                unsigned pos = atomicAdd(&sn, 1u);
                if (pos < (unsigned)SCAP) {
                    unsigned pg = (unsigned)(p0 + pj);
                    skey[pos] = ((unsigned long long)__float_as_uint(sv) << 32) | (~pg);
                    scls[pos] = (unsigned short)cj;
                    atomicAdd(&scnt[cj], 1u);
                } else {
                    bflag[b] = 1u;              // staging overflow -> image fallback
                }
            }
        }
    }
    __syncthreads();
    if (tid < C_) sbase[tid] = scnt[tid] ? atomicAdd(&cnt[b * C_ + tid], scnt[tid]) : 0u;
    __syncthreads();
    const int m = (int)min(sn, (unsigned)SCAP);
    for (int i = tid; i < m; i += 256) {
        int c = scls[i];
        unsigned pos = sbase[c] + atomicAdd(&scnt2[c], 1u);
        if (pos < (unsigned)CAP)
            cand[((size_t)(b * C_ + c)) * CAP + pos] = skey[i];
        // pos >= CAP  =>  cnt[task] > CAP  => task falls back (detected in k_nms)
    }
}

// ---------------------------------------------------------------------------
// K2: per-task radix-digit cut -> barrier-free rank-sort (exact top-200),
// decode, IoU masks (float4 boxes, register-cached columns), wave-0 greedy
// scan, compacted coalesced write. ~9 block barriers total on the hot path.
// ---------------------------------------------------------------------------
__global__ __launch_bounds__(256) void k_nms(const unsigned long long* __restrict__ cand,
                                             const unsigned* __restrict__ cnt,
                                             const unsigned* __restrict__ bflag,
                                             const float* __restrict__ conf,
                                             const float* __restrict__ loc,
                                             const float* __restrict__ prior,
                                             float* __restrict__ out) {
#pragma clang fp contract(off)
    __shared__ __align__(16) unsigned long long masks[K_][4];   // 6400 B
    __shared__ __align__(16) float outrow[1024];                // 4096 B; aliases buf[512] u64
    __shared__ __align__(16) unsigned long long top[256];       // 2048 B (cut survivors)
    __shared__ __align__(16) float4 bbox[K_];                   // 3200 B (x1,y1,x2,y2)
    __shared__ float sc[K_], bar[K_];
    __shared__ unsigned char vflag[K_];
    __shared__ unsigned long long keepw[4];
    __shared__ unsigned kpre[4];
    __shared__ unsigned long long sh_prefix;
    __shared__ unsigned sh_rank, sh_cnt2, sh_cut, sh_fat;

    unsigned long long* buf = (unsigned long long*)outrow;      // 512 u64 staging
    unsigned* rs_hist = (unsigned*)&masks[0][0];                // 1 KB (pre-IoU scratch)
    unsigned* rs_sf   = (unsigned*)&masks[32][0];               // 1 KB (fallback only)
    unsigned long long* srt = &masks[64][0];                    // 2 KB (rank-ordered keys)

    const int bid = blockIdx.x;
    const int b = bid / C_, c = bid % C_;
    const int tid = threadIdx.x;
    float* obase = out + ((size_t)(b * C_ + c)) * (K_ * 5);

    if (c == 0) {                               // background rows: all zeros
        float4 z = make_float4(0.f, 0.f, 0.f, 0.f);
        for (int i = tid; i < K_ * 5 / 4; i += 256) ((float4*)obase)[i] = z;
        return;
    }

    const int task = b * C_ + c;
    const unsigned long long* crow = cand + (size_t)task * CAP;
    const unsigned cn = cnt[task];
    const bool fb = (bflag[b] != 0u) || (cn < (unsigned)K_) || (cn > (unsigned)CAP);

    int n;
    if (!fb) {
        n = (int)cn;                            // 200 <= n <= CAP
        for (int i = tid; i < CAP; i += 256)
            buf[i] = (i < n) ? crow[i] : 0ull;
        top[tid] = 0ull;
        rs_hist[tid] = 0u;
        __syncthreads();
    } else {
        // ---- exact fallback from the strided global column (rare/never) ----
        for (int i = tid; i < CAP; i += 256) buf[i] = 0ull;
        top[tid] = 0ull;
        const float* col = conf + (size_t)b * P_ * C_ + c;
        unsigned lc = 0;
        for (int p = tid; p < P_; p += 256)
            if (col[(size_t)p * C_] > 0.01f) lc++;
        rs_sf[tid] = lc;
        __syncthreads();
        for (int off = 128; off > 0; off >>= 1) {
            if (tid < off) rs_sf[tid] += rs_sf[tid + off];
            __syncthreads();
        }
        const unsigned total = rs_sf[0];
        unsigned long long t200v = 1ull;
        if (total > (unsigned)K_) {
            if (tid == 0) { sh_prefix = 0ull; sh_rank = (unsigned)K_; }
            __syncthreads();
            for (int d = 7; d >= 0; --d) {
                rs_hist[tid] = 0;
                __syncthreads();
                const unsigned long long pref = sh_prefix;
                const unsigned rank = sh_rank;
                for (int p = tid; p < P_; p += 256) {
                    float sv = col[(size_t)p * C_];
                    if (sv > 0.01f) {
                        unsigned long long key =
                            ((unsigned long long)__float_as_uint(sv) << 32) | (~(unsigned)p);
                        bool match = (d == 7) || (((key ^ pref) >> ((d + 1) * 8)) == 0ull);
                        if (match) atomicAdd(&rs_hist[(unsigned)((key >> (d * 8)) & 255ull)], 1u);
                    }
                }
                __syncthreads();
                rs_sf[tid] = rs_hist[tid];
                __syncthreads();
                for (int off = 1; off < 256; off <<= 1) {
                    unsigned v2 = (tid + off < 256) ? rs_sf[tid + off] : 0u;
                    __syncthreads();
                    rs_sf[tid] += v2;
                    __syncthreads();
                }
                if (rs_sf[tid] >= rank && (tid == 255 || rs_sf[tid + 1] < rank)) {
                    sh_prefix = pref | ((unsigned long long)tid << (d * 8));
                    sh_rank = rank - ((tid == 255) ? 0u : rs_sf[tid + 1]);
                }
                __syncthreads();
            }
            t200v = sh_prefix;
        }
        if (tid == 0) sh_cnt2 = 0;
        __syncthreads();
        for (int p = tid; p < P_; p += 256) {
            float sv = col[(size_t)p * C_];
            if (sv > 0.01f) {
                unsigned long long key =
                    ((unsigned long long)__float_as_uint(sv) << 32) | (~(unsigned)p);
                if (key >= t200v) {
                    unsigned pos = atomicAdd(&sh_cnt2, 1u);
                    if (pos < (unsigned)CAP) buf[pos] = key;   // <=200 qualify (keys unique)
                }
            }
        }
        __syncthreads();
        n = (int)min(sh_cnt2, (unsigned)CAP);   // <= 200
    }

    // ---- working set <=256 via exact radix-digit cut ------------------------
    bool fat = false;
    if (n <= 256) {
        top[tid] = (tid < n) ? buf[tid] : 0ull;
        __syncthreads();
    } else {
        for (int i = tid; i < n; i += 256)
            atomicAdd(&rs_hist[(unsigned)((buf[i] >> 43) & 255ull)], 1u);
        __syncthreads();
        // wave-0 suffix scan over 256 bins (4 bins/lane), pick cut digit
        if (tid < 64) {
            const int l = tid;
            uint4 h = *(const uint4*)&rs_hist[l * 4];
            unsigned s3 = h.w;
            unsigned s2 = h.z + s3;
            unsigned s1 = h.y + s2;
            unsigned s0 = h.x + s1;
            unsigned acc = s0;
            for (int off = 1; off < 64; off <<= 1) {
                unsigned o = __shfl_down(acc, off, 64);
                if (l + off < 64) acc += o;
            }
            const unsigned suf_after = acc - s0;     // sum over lanes > l
            unsigned long long bal = __ballot(s0 + suf_after >= (unsigned)K_);
            int hl = 63 - __builtin_clzll(bal);      // bal != 0: lane 0 suffix = n >= 257
            if (l == hl) {
                int k; unsigned sufk;
                if      (s3 + suf_after >= (unsigned)K_) { k = 3; sufk = s3 + suf_after; }
                else if (s2 + suf_after >= (unsigned)K_) { k = 2; sufk = s2 + suf_after; }
                else if (s1 + suf_after >= (unsigned)K_) { k = 1; sufk = s1 + suf_after; }
                else                                     { k = 0; sufk = s0 + suf_after; }
                sh_cut = (unsigned)(l * 4 + k);
                sh_fat = (sufk > 256u) ? 1u : 0u;
                sh_cnt2 = 0u;
            }
        }
        __syncthreads();
        fat = (sh_fat != 0u);
        if (!fat) {
            const unsigned cut = sh_cut;
            for (int i = tid; i < n; i += 256) {
                unsigned long long key = buf[i];
                if ((unsigned)((key >> 43) & 255ull) >= cut)
                    top[atomicAdd(&sh_cnt2, 1u)] = key;   // 200..256 keys, exact set
            }
            __syncthreads();
        }
    }

    // ---- barrier-free exact rank-sort (keys unique => unique ranks) --------
    if (!fat) {
        const unsigned long long k1 = top[tid];
        int r1 = 0;
        for (int i = 0; i < 256; i += 4) {
            ulonglong2 a  = *(const ulonglong2*)&top[i];
            ulonglong2 b2 = *(const ulonglong2*)&top[i + 2];
            r1 += (a.x > k1) + (a.y > k1) + (b2.x > k1) + (b2.y > k1);
        }
        if (k1 != 0ull) srt[r1] = k1;
    } else {
        // degenerate digit distribution (essentially never): 2-key rank over 512
        const unsigned long long k1 = buf[tid];
        const unsigned long long k2 = buf[tid + 256];
        int r1 = 0, r2 = 0;
        for (int i = 0; i < 512; i += 4) {
            ulonglong2 a  = *(const ulonglong2*)&buf[i];
            ulonglong2 b2 = *(const ulonglong2*)&buf[i + 2];
            r1 += (a.x > k1) + (a.y > k1) + (b2.x > k1) + (b2.y > k1);
            r2 += (a.x > k2) + (a.y > k2) + (b2.x > k2) + (b2.y > k2);
        }
        if (k1 != 0ull && r1 < 256) srt[r1] = k1;
        if (k2 != 0ull && r2 < 256) srt[r2] = k2;
    }
    __syncthreads();

    const int nsel = min(n, K_);

    // decode rank-r candidates (srt[r] = (r+1)-th largest key)
    if (tid < K_) {
        const int r = tid;
        bool v = (r < nsel);
        float score = 0.f, x1 = 0.f, y1 = 0.f, x2 = 0.f, y2 = 0.f, ar = 0.f;
        if (v) {
            unsigned long long key = srt[r];
            unsigned ub = (unsigned)(key >> 32);
            unsigned p = ~((unsigned)key);
            score = __uint_as_float(ub);
            v = ((ub & 0x7F800000u) != 0x7F800000u);   // isfinite
            const float4 l4 = ((const float4*)loc)[(size_t)b * P_ + p];
            const float4 p4 = ((const float4*)prior)[p];
            float cx = p4.x + (l4.x * 0.1f) * p4.z;
            float cy = p4.y + (l4.y * 0.1f) * p4.w;
            float w  = p4.z * expf(l4.z * 0.2f);
            float h  = p4.w * expf(l4.w * 0.2f);
            x1 = cx - w * 0.5f;
            y1 = cy - h * 0.5f;
            x2 = x1 + w;
            y2 = y1 + h;
            ar = (x2 - x1) * (y2 - y1);
        }
        bbox[r] = make_float4(x1, y1, x2, y2);
        sc[r] = score; bar[r] = ar;
        vflag[r] = v ? (unsigned char)1 : (unsigned char)0;
    }
    __syncthreads();                            // srt dead -> masks writable; buf dead

    {
        float4 z = make_float4(0.f, 0.f, 0.f, 0.f);
        ((float4*)outrow)[tid] = z;             // 256 float4 = 1024 floats
    }

    // ---- IoU suppression bitmasks, float4 rows, register-cached columns ----
    const int nv = nsel;
    const int wid = tid >> 6, lane = tid & 63;

    float4 jb[4]; float jar[4];
#pragma unroll
    for (int w = 0; w < 4; ++w) {
        int j = w * 64 + lane;
        bool in = (j < K_);
        jb[w]  = in ? bbox[j] : make_float4(0.f, 0.f, 0.f, 0.f);
        jar[w] = in ? bar[j] : 0.f;
    }

    for (int idx = tid; idx < K_ * 4; idx += 256) {
        int i = idx >> 2, w = idx & 3;
        if (w < (i >> 6)) masks[i][w] = 0ull;
    }
    for (int i = wid; i < nv; i += 4) {
        float4 rb = bbox[i];
        float r_ar = bar[i];
        const int w0 = i >> 6;
#pragma unroll
        for (int w = 0; w < 4; ++w) {
            if (w >= w0) {
                int j = w * 64 + lane;
                bool pred = false;
                if (j < nv && j > i) {
                    float xx1 = fmaxf(rb.x, jb[w].x);
                    float yy1 = fmaxf(rb.y, jb[w].y);
                    float xx2 = fminf(rb.z, jb[w].z);
                    float yy2 = fminf(rb.w, jb[w].w);
                    float iw = fmaxf(xx2 - xx1, 0.0f);
                    float ih = fmaxf(yy2 - yy1, 0.0f);
                    float inter = iw * ih;
                    float uni = (r_ar + jar[w]) - inter;
                    pred = (uni > 0.0f) && (inter / uni > 0.45f);
                }
                unsigned long long m = __ballot(pred);
                if (lane == 0) masks[i][w] = m;
            }
        }
    }
    __syncthreads();

    // ---- greedy suppression: wave 0, uniform lanes, kept-nonzero-rows loop.
    if (tid < 64) {
        const int l = tid;
        unsigned long long V0 = __ballot((l       < nv) && vflag[l]);
        unsigned long long V1 = __ballot((64 + l  < nv) && vflag[64 + l]);
        unsigned long long V2 = __ballot((128 + l < nv) && vflag[128 + l]);
        unsigned long long V3 = __ballot((192 + l < nv) && vflag[192 + l]);
        auto rownz = [&](int r) -> bool {
            if (r >= nv) return false;
            return (masks[r][0] | masks[r][1] | masks[r][2] | masks[r][3]) != 0ull;
        };
        unsigned long long R0 = __ballot(rownz(l))       & V0;
        unsigned long long R1 = __ballot(rownz(64 + l))  & V1;
        unsigned long long R2 = __ballot(rownz(128 + l)) & V2;
        unsigned long long R3 = __ballot(rownz(192 + l)) & V3;

        unsigned long long S0 = 0, S1 = 0, S2 = 0, S3 = 0;
        while (true) {
            unsigned long long t;
            int i = -1;
            if ((t = R0 & ~S0) != 0ull)      i = (int)__builtin_ctzll(t);
            else if ((t = R1 & ~S1) != 0ull) i = 64 + (int)__builtin_ctzll(t);
            else if ((t = R2 & ~S2) != 0ull) i = 128 + (int)__builtin_ctzll(t);
            else if ((t = R3 & ~S3) != 0ull) i = 192 + (int)__builtin_ctzll(t);
            if (i < 0) break;
            const unsigned long long bit = 1ull << (i & 63);
            const int slot = i >> 6;
            if (slot == 0) R0 ^= bit; else if (slot == 1) R1 ^= bit;
            else if (slot == 2) R2 ^= bit; else R3 ^= bit;
            ulonglong2 m01 = *(const ulonglong2*)&masks[i][0];
            ulonglong2 m23 = *(const ulonglong2*)&masks[i][2];
            S0 |= m01.x; S1 |= m01.y; S2 |= m23.x; S3 |= m23.y;
        }
        if (l == 0) {
            unsigned long long K0 = V0 & ~S0, K1 = V1 & ~S1, K2 = V2 & ~S2, K3 = V3 & ~S3;
            keepw[0] = K0; keepw[1] = K1; keepw[2] = K2; keepw[3] = K3;
            kpre[0] = 0;
            kpre[1] = (unsigned)__popcll(K0);
            kpre[2] = kpre[1] + (unsigned)__popcll(K1);
            kpre[3] = kpre[2] + (unsigned)__popcll(K2);
        }
    }
    __syncthreads();

    if (tid < nv) {
        int w = tid >> 6, bit = tid & 63;
        if ((keepw[w] >> bit) & 1ull) {
            unsigned slot = kpre[w] + (unsigned)__popcll(keepw[w] & ((1ull << bit) - 1ull));
            float4 bb = bbox[tid];
            outrow[slot * 5 + 0] = sc[tid];
            outrow[slot * 5 + 1] = bb.x;
            outrow[slot * 5 + 2] = bb.y;
            outrow[slot * 5 + 3] = bb.z;
            outrow[slot * 5 + 4] = bb.w;
        }
    }
    __syncthreads();

    for (int i = tid; i < K_ * 5 / 4; i += 256)
        ((float4*)obase)[i] = ((const float4*)outrow)[i];
}

// ---------------------------------------------------------------------------
extern "C" void kernel_launch(void* const* d_in, const int* in_sizes, int n_in,
                              void* d_out, int out_size, void* d_ws, size_t ws_size,
                              hipStream_t stream) {
    const float* loc   = (const float*)d_in[0];
    const float* conf  = (const float*)d_in[1];
    const float* prior = (const float*)d_in[2];
    float* out = (float*)d_out;

    char* ws = (char*)d_ws;
    const size_t candBytes = (size_t)B_ * C_ * CAP * sizeof(unsigned long long); // 10.6 MB
    unsigned long long* cand = (unsigned long long*)ws;
    unsigned* cnt   = (unsigned*)(ws + candBytes);            // B_*C_ counters
    unsigned* bflag = cnt + (size_t)B_ * C_;                  // B_ flags (contiguous)

    hipMemsetAsync(cnt, 0, (size_t)(B_ * C_ + B_) * sizeof(unsigned), stream);

    k_filter<<<B_ * NCH, 256, 0, stream>>>(conf, cand, cnt, bflag);
    k_nms   <<<B_ * C_,  256, 0, stream>>>(cand, cnt, bflag, conf, loc, prior, out);
}